// Round 1
// baseline (127.318 us; speedup 1.0000x reference)
//
#include <hip/hip_runtime.h>
#include <math.h>

#define N_PTS 1024
#define D 128
#define QL 400
#define PLD 1200            // 3*QL
#define SQRT_D_INV 0.08838834764831845f  // 1/sqrt(128)

// ---------------- GEMM NT: C[m,n] = sum_k A[m,k] * B[n,k] ----------------
// A: M x K row-major (lda), B: N x K row-major (ldb), C: M x N (ldc)
// 64x64 tile, 256 threads, 4x4 micro-tile, BK=16, transposed LDS (+4 pad).
template<int BM, int BN, int BK>
__global__ __launch_bounds__(256) void gemm_nt_kernel(
    const float* __restrict__ A, int lda,
    const float* __restrict__ B, int ldb,
    float* __restrict__ C, int ldc,
    int M, int Nn, int K)
{
    __shared__ float As[BK][BM + 4];
    __shared__ float Bs[BK][BN + 4];
    const int tid = threadIdx.x;
    const int bm = blockIdx.y * BM;
    const int bn = blockIdx.x * BN;
    const int tr = (tid / (BN / 4)) * 4;
    const int tc = (tid % (BN / 4)) * 4;
    float acc[4][4] = {};

    for (int k0 = 0; k0 < K; k0 += BK) {
        #pragma unroll
        for (int e = tid; e < BM * BK; e += 256) {
            int r = e / BK, c = e % BK;
            int gm = bm + r;
            As[c][r] = (gm < M) ? A[(size_t)gm * lda + k0 + c] : 0.0f;
        }
        #pragma unroll
        for (int e = tid; e < BN * BK; e += 256) {
            int r = e / BK, c = e % BK;
            int gn = bn + r;
            Bs[c][r] = (gn < Nn) ? B[(size_t)gn * ldb + k0 + c] : 0.0f;
        }
        __syncthreads();
        #pragma unroll
        for (int kk = 0; kk < BK; ++kk) {
            float4 a4 = *(const float4*)&As[kk][tr];
            float4 b4 = *(const float4*)&Bs[kk][tc];
            float av[4] = {a4.x, a4.y, a4.z, a4.w};
            float bv[4] = {b4.x, b4.y, b4.z, b4.w};
            #pragma unroll
            for (int i = 0; i < 4; ++i)
                #pragma unroll
                for (int j = 0; j < 4; ++j)
                    acc[i][j] += av[i] * bv[j];
        }
        __syncthreads();
    }
    #pragma unroll
    for (int i = 0; i < 4; ++i) {
        int gm = bm + tr + i;
        if (gm >= M) continue;
        #pragma unroll
        for (int j = 0; j < 4; ++j) {
            int gn = bn + tc + j;
            if (gn < Nn) C[(size_t)gm * ldc + gn] = acc[i][j];
        }
    }
}

// ---------------- GEMM NN: C[m,n] = sum_k A[m,k] * B[k,n] (+bias[n]) ------
// Split-K via gridDim.z: block z covers K-chunk z, writes to C + z*M*ldc.
template<int BM, int BN, int BK>
__global__ __launch_bounds__(256) void gemm_nn_kernel(
    const float* __restrict__ A, int lda,
    const float* __restrict__ B, int ldb,
    const float* __restrict__ bias,
    float* __restrict__ C, int ldc,
    int M, int Nn, int K)
{
    __shared__ float As[BK][BM + 4];
    __shared__ float Bs[BK][BN + 4];
    const int tid = threadIdx.x;
    const int bm = blockIdx.y * BM;
    const int bn = blockIdx.x * BN;
    const int kchunk = K / gridDim.z;
    const int kbeg = blockIdx.z * kchunk;
    const int kend = kbeg + kchunk;
    float* Cz = C + (size_t)blockIdx.z * ((size_t)M * ldc);
    const int tr = (tid / (BN / 4)) * 4;
    const int tc = (tid % (BN / 4)) * 4;
    float acc[4][4] = {};

    for (int k0 = kbeg; k0 < kend; k0 += BK) {
        #pragma unroll
        for (int e = tid; e < BM * BK; e += 256) {
            int r = e / BK, c = e % BK;
            int gm = bm + r;
            As[c][r] = (gm < M) ? A[(size_t)gm * lda + k0 + c] : 0.0f;
        }
        #pragma unroll
        for (int e = tid; e < BK * BN; e += 256) {
            int r = e / BN, c = e % BN;
            int gn = bn + c;
            Bs[r][c] = (gn < Nn) ? B[(size_t)(k0 + r) * ldb + gn] : 0.0f;
        }
        __syncthreads();
        #pragma unroll
        for (int kk = 0; kk < BK; ++kk) {
            float4 a4 = *(const float4*)&As[kk][tr];
            float4 b4 = *(const float4*)&Bs[kk][tc];
            float av[4] = {a4.x, a4.y, a4.z, a4.w};
            float bv[4] = {b4.x, b4.y, b4.z, b4.w};
            #pragma unroll
            for (int i = 0; i < 4; ++i)
                #pragma unroll
                for (int j = 0; j < 4; ++j)
                    acc[i][j] += av[i] * bv[j];
        }
        __syncthreads();
    }
    #pragma unroll
    for (int i = 0; i < 4; ++i) {
        int gm = bm + tr + i;
        if (gm >= M) continue;
        #pragma unroll
        for (int j = 0; j < 4; ++j) {
            int gn = bn + tc + j;
            if (gn < Nn) {
                float v = acc[i][j];
                if (bias) v += bias[gn];
                Cz[(size_t)gm * ldc + gn] = v;
            }
        }
    }
}

// ---------------- Attention row kernel -----------------------------------
// One block per row i. Stages P-row (1200 f32) in LDS, computes scores for
// all j with LDS bias gathers, block softmax, writes attn weights into S
// in place.
__global__ __launch_bounds__(256) void attn_rows_kernel(
    const float* __restrict__ vd,   // N x N x 3
    const float* __restrict__ P,    // N x 1200
    float* __restrict__ S)          // N x N: in = raw q.k, out = attn weights
{
    const int i = blockIdx.x;
    const int tid = threadIdx.x;
    __shared__ float Pl[PLD];
    __shared__ float redmax[4];
    __shared__ float redsum[4];

    for (int e = tid; e < PLD; e += 256) Pl[e] = P[(size_t)i * PLD + e];
    __syncthreads();

    const float* vdi = vd + (size_t)i * N_PTS * 3;
    float* Si = S + (size_t)i * N_PTS;

    // thread handles j = 4*tid .. 4*tid+3 : fully coalesced float4 loads
    float4 d0 = *(const float4*)&vdi[12 * tid + 0];
    float4 d1 = *(const float4*)&vdi[12 * tid + 4];
    float4 d2 = *(const float4*)&vdi[12 * tid + 8];
    float dv[12] = {d0.x, d0.y, d0.z, d0.w,
                    d1.x, d1.y, d1.z, d1.w,
                    d2.x, d2.y, d2.z, d2.w};
    float4 s0 = *(const float4*)&Si[4 * tid];
    float sraw[4] = {s0.x, s0.y, s0.z, s0.w};

    float sc[4];
    float mx = -3.0e38f;
    #pragma unroll
    for (int w = 0; w < 4; ++w) {
        float x = dv[3 * w + 0];
        float y = dv[3 * w + 1];
        float z = dv[3 * w + 2];
        int ix = (int)floorf((x + 4.0f) / 0.02f);
        int iy = (int)floorf((y + 4.0f) / 0.02f);
        int iz = (int)floorf((z + 4.0f) / 0.02f);
        ix = min(max(ix, 0), QL - 1);
        iy = min(max(iy, 0), QL - 1);
        iz = min(max(iz, 0), QL - 1);
        float b = Pl[ix] + Pl[QL + iy] + Pl[2 * QL + iz];
        float s = (sraw[w] + b) * SQRT_D_INV;
        sc[w] = s;
        mx = fmaxf(mx, s);
    }

    // block-wide max
    #pragma unroll
    for (int o = 32; o > 0; o >>= 1) mx = fmaxf(mx, __shfl_xor(mx, o));
    if ((tid & 63) == 0) redmax[tid >> 6] = mx;
    __syncthreads();
    mx = fmaxf(fmaxf(redmax[0], redmax[1]), fmaxf(redmax[2], redmax[3]));

    float ev[4];
    float ssum = 0.0f;
    #pragma unroll
    for (int w = 0; w < 4; ++w) {
        ev[w] = __expf(sc[w] - mx);
        ssum += ev[w];
    }
    #pragma unroll
    for (int o = 32; o > 0; o >>= 1) ssum += __shfl_xor(ssum, o);
    if ((tid & 63) == 0) redsum[tid >> 6] = ssum;
    __syncthreads();
    float tot = redsum[0] + redsum[1] + redsum[2] + redsum[3];
    float inv = 1.0f / tot;

    float4 o4 = make_float4(ev[0] * inv, ev[1] * inv, ev[2] * inv, ev[3] * inv);
    *(float4*)&Si[4 * tid] = o4;
}

// ---------------- Split-K partial reduce ----------------------------------
__global__ __launch_bounds__(256) void reduce_parts_kernel(
    const float* __restrict__ part, float* __restrict__ out,
    int total4, int nparts)
{
    int e = blockIdx.x * 256 + threadIdx.x;
    if (e >= total4) return;
    const float4* p4 = (const float4*)part;
    float4 acc = p4[e];
    for (int s = 1; s < nparts; ++s) {
        float4 v = p4[(size_t)s * total4 + e];
        acc.x += v.x; acc.y += v.y; acc.z += v.z; acc.w += v.w;
    }
    ((float4*)out)[e] = acc;
}

extern "C" void kernel_launch(void* const* d_in, const int* in_sizes, int n_in,
                              void* d_out, int out_size, void* d_ws, size_t ws_size,
                              hipStream_t stream)
{
    const float* features = (const float*)d_in[0];  // 1024 x 128
    const float* vd       = (const float*)d_in[1];  // 1024 x 1024 x 3
    const float* W        = (const float*)d_in[2];  // 128 x 384
    const float* b        = (const float*)d_in[3];  // 384
    const float* tx       = (const float*)d_in[4];  // 3 x 400 x 128
    const float* ty       = (const float*)d_in[5];
    const float* tz       = (const float*)d_in[6];
    float* out = (float*)d_out;                     // 1024 x 128
    float* ws = (float*)d_ws;

    float* qkv  = ws;                               // 1024*384  (q|k|v rows)
    float* P    = qkv + (size_t)N_PTS * 384;        // 1024*1200
    float* S    = P + (size_t)N_PTS * PLD;          // 1024*1024
    float* part = S + (size_t)N_PTS * N_PTS;        // 8 * 1024*128

    dim3 blk(256);

    // 1. qkv = features @ W + b   (M=1024, N=384, K=128)
    gemm_nn_kernel<64, 64, 16><<<dim3(384 / 64, N_PTS / 64, 1), blk, 0, stream>>>(
        features, D, W, 384, b, qkv, 384, N_PTS, 384, D);

    // 2-4. P sections: P[:, s*400:(s+1)*400] = k @ table_s[1]^T
    gemm_nt_kernel<64, 64, 16><<<dim3((QL + 63) / 64, N_PTS / 64), blk, 0, stream>>>(
        qkv + D, 384, tx + QL * D, D, P + 0 * QL, PLD, N_PTS, QL, D);
    gemm_nt_kernel<64, 64, 16><<<dim3((QL + 63) / 64, N_PTS / 64), blk, 0, stream>>>(
        qkv + D, 384, ty + QL * D, D, P + 1 * QL, PLD, N_PTS, QL, D);
    gemm_nt_kernel<64, 64, 16><<<dim3((QL + 63) / 64, N_PTS / 64), blk, 0, stream>>>(
        qkv + D, 384, tz + QL * D, D, P + 2 * QL, PLD, N_PTS, QL, D);

    // 5. S = q @ k^T (unscaled)
    gemm_nt_kernel<64, 64, 16><<<dim3(N_PTS / 64, N_PTS / 64), blk, 0, stream>>>(
        qkv, 384, qkv + D, 384, S, N_PTS, N_PTS, N_PTS, D);

    // 6. scores + softmax -> attn weights (in place in S)
    attn_rows_kernel<<<dim3(N_PTS), blk, 0, stream>>>(vd, P, S);

    // 7. out partials = attn @ v, split-K = 8 (256 blocks)
    gemm_nn_kernel<64, 64, 16><<<dim3(D / 64, N_PTS / 64, 8), blk, 0, stream>>>(
        S, N_PTS, qkv + 2 * D, 384, nullptr, part, D, N_PTS, D, N_PTS);

    // 8. reduce partials -> out
    reduce_parts_kernel<<<dim3((N_PTS * D / 4) / 256), blk, 0, stream>>>(
        part, out, N_PTS * D / 4, 8);
}

// Round 2
// 37.858 us; speedup vs baseline: 3.3630x; 3.3630x over previous
//
#include <hip/hip_runtime.h>
#include <math.h>

#define N_PTS 1024
#define D 128
#define QL 400
#define PLD 1200            // 3*QL
#define SQRT_D_INV 0.08838834764831845f

typedef __attribute__((ext_vector_type(8))) short bf16x8;
typedef __attribute__((ext_vector_type(4))) float f32x4;
typedef unsigned short u16;

#define GLOBAL_AS __attribute__((address_space(1)))
#define LDS_AS    __attribute__((address_space(3)))

__device__ __forceinline__ u16 f2bf(float x) {
    union { float f; unsigned u; } v; v.f = x;
    unsigned r = v.u + 0x7fff + ((v.u >> 16) & 1);   // RNE
    return (u16)(r >> 16);
}

// ------------------------------------------------------------------
// Convert/pack kernel: features->bf16, W(128x384)->Wt(384x128) bf16,
// tables[1] x,y,z -> Tcat(1200x128) bf16.
// ------------------------------------------------------------------
#define CVT_F 131072            // 1024*128
#define CVT_W 49152             // 384*128
#define CVT_T 153600            // 1200*128
__global__ __launch_bounds__(256) void convert_kernel(
    const float* __restrict__ features, const float* __restrict__ W,
    const float* __restrict__ tx, const float* __restrict__ ty,
    const float* __restrict__ tz,
    u16* __restrict__ fbf, u16* __restrict__ Wt, u16* __restrict__ Tcat)
{
    int e = blockIdx.x * 256 + threadIdx.x;
    if (e < CVT_F) {
        fbf[e] = f2bf(features[e]);
        return;
    }
    int e2 = e - CVT_F;
    if (e2 < CVT_W) {
        int n = e2 >> 7, k = e2 & 127;
        Wt[e2] = f2bf(W[k * 384 + n]);
        return;
    }
    int e3 = e2 - CVT_W;
    if (e3 < CVT_T) {
        int n = e3 >> 7, k = e3 & 127;
        int sec = n / QL, r = n - sec * QL;
        const float* t = (sec == 0) ? tx : ((sec == 1) ? ty : tz);
        Tcat[e3] = f2bf(t[QL * D + r * D + k]);   // section [1] of table
    }
}

// ------------------------------------------------------------------
// MFMA GEMM-NT: C[m,n] = sum_k A[m,k] * B[n,k]
// A: M x lda bf16 row-major, B: Nn x ldb bf16 row-major.
// Tile 64x64, BK=128 per stage. 256 threads = 4 waves (2x2), each wave
// computes 32x32 via 2x2 fragments of 16x16x32 MFMA.
// LDS tiles stored with col16 ^= (row&7) swizzle (applied on the global
// source address since global_load_lds writes linearly).
// EPI 0: C[grow*ldc+gcol] = acc (guard gcol<Nn)
// EPI 1: qkv epilogue: +bias, split cols into q/k bf16 and vT bf16.
// ------------------------------------------------------------------
template<int EPI>
__global__ __launch_bounds__(256) void mfma_nt(
    const u16* __restrict__ A, int lda,
    const u16* __restrict__ B, int ldb, int Nn,
    float* __restrict__ C, int ldc, int Ktot,
    const float* __restrict__ bias,
    u16* __restrict__ qb, u16* __restrict__ kb, u16* __restrict__ vT)
{
    __shared__ __align__(16) u16 As[64 * 128];
    __shared__ __align__(16) u16 Bs[64 * 128];
    const int tid  = threadIdx.x;
    const int wave = tid >> 6, lane = tid & 63;
    const int wr = wave >> 1, wc = wave & 1;
    const int l15 = lane & 15, l4 = lane >> 4;
    const int bm = blockIdx.y * 64, bn = blockIdx.x * 64;

    f32x4 acc[2][2] = {};

    // per-lane staging geometry (same for all rounds): row/col from 16B unit id
    for (int k0 = 0; k0 < Ktot; k0 += 128) {
        if (k0) __syncthreads();      // protect prev-iter reads before overwrite
        #pragma unroll
        for (int r = 0; r < 4; ++r) {
            int unit = r * 256 + tid;        // 16-byte unit id, 0..1023
            int row  = unit >> 4;            // 0..63
            int c16  = unit & 15;            // 16B column within 256B row
            int csw  = c16 ^ (row & 7);      // pre-swizzled source column
            // A rows always in-bounds (M multiple of 64)
            const u16* ga = A + (size_t)(bm + row) * lda + k0 + csw * 8;
            __builtin_amdgcn_global_load_lds(
                (const GLOBAL_AS unsigned int*)ga,
                (LDS_AS unsigned int*)(As + r * 2048 + wave * 512), 16, 0, 0);
            int brow = bn + row; if (brow > Nn - 1) brow = Nn - 1;  // clamp edge
            const u16* gb = B + (size_t)brow * ldb + k0 + csw * 8;
            __builtin_amdgcn_global_load_lds(
                (const GLOBAL_AS unsigned int*)gb,
                (LDS_AS unsigned int*)(Bs + r * 2048 + wave * 512), 16, 0, 0);
        }
        __syncthreads();

        #pragma unroll
        for (int ks = 0; ks < 4; ++ks) {
            bf16x8 a[2], b[2];
            #pragma unroll
            for (int m = 0; m < 2; ++m) {
                int row = wr * 32 + m * 16 + l15;
                int c16 = ks * 4 + l4;
                a[m] = *(const bf16x8*)(As + row * 128 + (c16 ^ (row & 7)) * 8);
            }
            #pragma unroll
            for (int n = 0; n < 2; ++n) {
                int row = wc * 32 + n * 16 + l15;
                int c16 = ks * 4 + l4;
                b[n] = *(const bf16x8*)(Bs + row * 128 + (c16 ^ (row & 7)) * 8);
            }
            #pragma unroll
            for (int m = 0; m < 2; ++m)
                #pragma unroll
                for (int n = 0; n < 2; ++n)
                    acc[m][n] = __builtin_amdgcn_mfma_f32_16x16x32_bf16(
                        a[m], b[n], acc[m][n], 0, 0, 0);
        }
    }

    #pragma unroll
    for (int m = 0; m < 2; ++m) {
        #pragma unroll
        for (int n = 0; n < 2; ++n) {
            #pragma unroll
            for (int r = 0; r < 4; ++r) {
                int grow = bm + wr * 32 + m * 16 + l4 * 4 + r;
                int gcol = bn + wc * 32 + n * 16 + l15;
                float val = acc[m][n][r];
                if (EPI == 0) {
                    if (gcol < Nn) C[(size_t)grow * ldc + gcol] = val;
                } else {
                    val += bias[gcol];
                    int reg = gcol >> 7, lc = gcol & 127;
                    u16 h = f2bf(val);
                    if (reg == 0)      qb[grow * D + lc] = h;
                    else if (reg == 1) kb[grow * D + lc] = h;
                    else               vT[lc * N_PTS + grow] = h;
                }
            }
        }
    }
}

// ------------------------------------------------------------------
// Attention rows: per row i, stage P-row in LDS, bias-gather + scale,
// block softmax, write bf16 attention weights.
// ------------------------------------------------------------------
__global__ __launch_bounds__(256) void attn_rows_kernel(
    const float* __restrict__ vd,   // N x N x 3
    const float* __restrict__ P,    // N x 1200 f32
    const float* __restrict__ S,    // N x N raw q.k f32
    u16* __restrict__ Sb)           // N x N bf16 attn weights out
{
    const int i = blockIdx.x;
    const int tid = threadIdx.x;
    __shared__ float Pl[PLD];
    __shared__ float redmax[4];
    __shared__ float redsum[4];

    for (int e = tid; e < PLD; e += 256) Pl[e] = P[(size_t)i * PLD + e];
    __syncthreads();

    const float* vdi = vd + (size_t)i * N_PTS * 3;
    const float* Si = S + (size_t)i * N_PTS;

    float4 d0 = *(const float4*)&vdi[12 * tid + 0];
    float4 d1 = *(const float4*)&vdi[12 * tid + 4];
    float4 d2 = *(const float4*)&vdi[12 * tid + 8];
    float dv[12] = {d0.x, d0.y, d0.z, d0.w,
                    d1.x, d1.y, d1.z, d1.w,
                    d2.x, d2.y, d2.z, d2.w};
    float4 s0 = *(const float4*)&Si[4 * tid];
    float sraw[4] = {s0.x, s0.y, s0.z, s0.w};

    float sc[4];
    float mx = -3.0e38f;
    #pragma unroll
    for (int w = 0; w < 4; ++w) {
        int ix = (int)floorf((dv[3 * w + 0] + 4.0f) / 0.02f);
        int iy = (int)floorf((dv[3 * w + 1] + 4.0f) / 0.02f);
        int iz = (int)floorf((dv[3 * w + 2] + 4.0f) / 0.02f);
        ix = min(max(ix, 0), QL - 1);
        iy = min(max(iy, 0), QL - 1);
        iz = min(max(iz, 0), QL - 1);
        float b = Pl[ix] + Pl[QL + iy] + Pl[2 * QL + iz];
        float s = (sraw[w] + b) * SQRT_D_INV;
        sc[w] = s;
        mx = fmaxf(mx, s);
    }

    #pragma unroll
    for (int o = 32; o > 0; o >>= 1) mx = fmaxf(mx, __shfl_xor(mx, o));
    if ((tid & 63) == 0) redmax[tid >> 6] = mx;
    __syncthreads();
    mx = fmaxf(fmaxf(redmax[0], redmax[1]), fmaxf(redmax[2], redmax[3]));

    float ev[4];
    float ssum = 0.0f;
    #pragma unroll
    for (int w = 0; w < 4; ++w) { ev[w] = __expf(sc[w] - mx); ssum += ev[w]; }
    #pragma unroll
    for (int o = 32; o > 0; o >>= 1) ssum += __shfl_xor(ssum, o);
    if ((tid & 63) == 0) redsum[tid >> 6] = ssum;
    __syncthreads();
    float inv = 1.0f / (redsum[0] + redsum[1] + redsum[2] + redsum[3]);

    ushort4 o4;
    o4.x = f2bf(ev[0] * inv);
    o4.y = f2bf(ev[1] * inv);
    o4.z = f2bf(ev[2] * inv);
    o4.w = f2bf(ev[3] * inv);
    *(ushort4*)&Sb[(size_t)i * N_PTS + 4 * tid] = o4;
}

// ------------------------------------------------------------------
extern "C" void kernel_launch(void* const* d_in, const int* in_sizes, int n_in,
                              void* d_out, int out_size, void* d_ws, size_t ws_size,
                              hipStream_t stream)
{
    const float* features = (const float*)d_in[0];  // 1024 x 128
    const float* vd       = (const float*)d_in[1];  // 1024 x 1024 x 3
    const float* W        = (const float*)d_in[2];  // 128 x 384
    const float* b        = (const float*)d_in[3];  // 384
    const float* tx       = (const float*)d_in[4];  // 3 x 400 x 128
    const float* ty       = (const float*)d_in[5];
    const float* tz       = (const float*)d_in[6];
    float* out = (float*)d_out;                     // 1024 x 128 f32

    // workspace layout (bytes, 256-aligned)
    char* w0 = (char*)d_ws;
    u16* fbf  = (u16*)w0;                                   // 131072*2
    u16* Wt   = (u16*)(w0 + 0x40000);                       // 49152*2
    u16* Tcat = (u16*)(w0 + 0x60000);                       // 153600*2
    u16* qb   = (u16*)(w0 + 0xB0000);                       // 131072*2
    u16* kb   = (u16*)(w0 + 0xF0000);                       // 131072*2
    u16* vT   = (u16*)(w0 + 0x130000);                      // 131072*2 (128x1024)
    u16* Sb   = (u16*)(w0 + 0x170000);                      // 1024*1024*2
    float* P  = (float*)(w0 + 0x370000);                    // 1024*1200*4
    float* S  = (float*)(w0 + 0x820000);                    // 1024*1024*4

    dim3 blk(256);

    // 0. converts
    convert_kernel<<<dim3((CVT_F + CVT_W + CVT_T) / 256), blk, 0, stream>>>(
        features, W, tx, ty, tz, fbf, Wt, Tcat);

    // 1. qkv = features @ W + b -> qb, kb bf16 and vT bf16 (transposed)
    mfma_nt<1><<<dim3(384 / 64, N_PTS / 64), blk, 0, stream>>>(
        fbf, D, Wt, D, 384, nullptr, 0, D, b, qb, kb, vT);

    // 2. P = k @ Tcat^T  (1024 x 1200)
    mfma_nt<0><<<dim3((PLD + 63) / 64, N_PTS / 64), blk, 0, stream>>>(
        kb, D, Tcat, D, PLD, P, PLD, D, nullptr, nullptr, nullptr, nullptr);

    // 3. S = q @ k^T (raw, unscaled)
    mfma_nt<0><<<dim3(N_PTS / 64, N_PTS / 64), blk, 0, stream>>>(
        qb, D, kb, D, N_PTS, S, N_PTS, D, nullptr, nullptr, nullptr, nullptr);

    // 4. scores + softmax -> bf16 attn weights
    attn_rows_kernel<<<dim3(N_PTS), blk, 0, stream>>>(vd, P, S, Sb);

    // 5. out = attn @ v  (A = Sb 1024x1024, B = vT 128x1024)
    mfma_nt<0><<<dim3(D / 64, N_PTS / 64), blk, 0, stream>>>(
        Sb, N_PTS, vT, N_PTS, D, out, D, N_PTS, nullptr, nullptr, nullptr, nullptr);
}

// Round 3
// 37.150 us; speedup vs baseline: 3.4272x; 1.0191x over previous
//
#include <hip/hip_runtime.h>
#include <math.h>

#define N_PTS 1024
#define D 128
#define QL 400
#define PLD 1200            // 3*QL
#define SQRT_D_INV 0.08838834764831845f

typedef __attribute__((ext_vector_type(8))) short bf16x8;
typedef __attribute__((ext_vector_type(4))) float f32x4;
typedef unsigned short u16;

#define GLOBAL_AS __attribute__((address_space(1)))
#define LDS_AS    __attribute__((address_space(3)))

__device__ __forceinline__ u16 f2bf(float x) {
    union { float f; unsigned u; } v; v.f = x;
    unsigned r = v.u + 0x7fff + ((v.u >> 16) & 1);   // RNE
    return (u16)(r >> 16);
}

// ------------------------------------------------------------------
// Convert/pack: features->bf16, W(128x384)->Wt(384x128) bf16,
// tables[1] x,y,z -> Tcat(1200x128) bf16.
// ------------------------------------------------------------------
#define CVT_F 131072            // 1024*128
#define CVT_W 49152             // 384*128
#define CVT_T 153600            // 1200*128
__global__ __launch_bounds__(256) void convert_kernel(
    const float* __restrict__ features, const float* __restrict__ W,
    const float* __restrict__ tx, const float* __restrict__ ty,
    const float* __restrict__ tz,
    u16* __restrict__ fbf, u16* __restrict__ Wt, u16* __restrict__ Tcat)
{
    int e = blockIdx.x * 256 + threadIdx.x;
    if (e < CVT_F) {
        fbf[e] = f2bf(features[e]);
        return;
    }
    int e2 = e - CVT_F;
    if (e2 < CVT_W) {
        int n = e2 >> 7, k = e2 & 127;
        Wt[e2] = f2bf(W[k * 384 + n]);
        return;
    }
    int e3 = e2 - CVT_W;
    if (e3 < CVT_T) {
        int n = e3 >> 7, k = e3 & 127;
        int sec = n / QL, r = n - sec * QL;
        const float* t = (sec == 0) ? tx : ((sec == 1) ? ty : tz);
        Tcat[e3] = f2bf(t[QL * D + r * D + k]);   // section [1]
    }
}

// ------------------------------------------------------------------
// MFMA GEMM-NT: C[m,n] = cscale * sum_k A[m,k]*B[n,k]  (64x64 tile, BK=128)
// Split-K via blockIdx.z pointer offsets kzA/kzB/kzC.
// EPI 0: f32 store (guard gcol<Nn), scaled by cscale.
// EPI 1: qkv epilogue: +bias, q scaled by 1/sqrt(D), split q/k/vT bf16.
// ------------------------------------------------------------------
template<int EPI>
__global__ __launch_bounds__(256) void mfma_nt(
    const u16* __restrict__ A, int lda,
    const u16* __restrict__ B, int ldb, int Nn,
    float* __restrict__ C, int ldc, int Ktot,
    const float* __restrict__ bias,
    u16* __restrict__ qb, u16* __restrict__ kb, u16* __restrict__ vT,
    int kzA, int kzB, long kzC, float cscale)
{
    __shared__ __align__(16) u16 As[64 * 128];
    __shared__ __align__(16) u16 Bs[64 * 128];
    const int tid  = threadIdx.x;
    const int wave = tid >> 6, lane = tid & 63;
    const int wr = wave >> 1, wc = wave & 1;
    const int l15 = lane & 15, l4 = lane >> 4;
    const int bm = blockIdx.y * 64, bn = blockIdx.x * 64;

    A += (size_t)blockIdx.z * kzA;
    B += (size_t)blockIdx.z * kzB;
    if (EPI == 0) C += (size_t)blockIdx.z * kzC;

    f32x4 acc[2][2] = {};

    for (int k0 = 0; k0 < Ktot; k0 += 128) {
        if (k0) __syncthreads();
        #pragma unroll
        for (int r = 0; r < 4; ++r) {
            int unit = r * 256 + tid;
            int row  = unit >> 4;
            int c16  = unit & 15;
            int csw  = c16 ^ (row & 7);
            const u16* ga = A + (size_t)(bm + row) * lda + k0 + csw * 8;
            __builtin_amdgcn_global_load_lds(
                (const GLOBAL_AS unsigned int*)ga,
                (LDS_AS unsigned int*)(As + r * 2048 + wave * 512), 16, 0, 0);
            int brow = bn + row; if (brow > Nn - 1) brow = Nn - 1;
            const u16* gb = B + (size_t)brow * ldb + k0 + csw * 8;
            __builtin_amdgcn_global_load_lds(
                (const GLOBAL_AS unsigned int*)gb,
                (LDS_AS unsigned int*)(Bs + r * 2048 + wave * 512), 16, 0, 0);
        }
        __syncthreads();

        #pragma unroll
        for (int ks = 0; ks < 4; ++ks) {
            bf16x8 a[2], b[2];
            #pragma unroll
            for (int m = 0; m < 2; ++m) {
                int row = wr * 32 + m * 16 + l15;
                int c16 = ks * 4 + l4;
                a[m] = *(const bf16x8*)(As + row * 128 + (c16 ^ (row & 7)) * 8);
            }
            #pragma unroll
            for (int n = 0; n < 2; ++n) {
                int row = wc * 32 + n * 16 + l15;
                int c16 = ks * 4 + l4;
                b[n] = *(const bf16x8*)(Bs + row * 128 + (c16 ^ (row & 7)) * 8);
            }
            #pragma unroll
            for (int m = 0; m < 2; ++m)
                #pragma unroll
                for (int n = 0; n < 2; ++n)
                    acc[m][n] = __builtin_amdgcn_mfma_f32_16x16x32_bf16(
                        a[m], b[n], acc[m][n], 0, 0, 0);
        }
    }

    #pragma unroll
    for (int m = 0; m < 2; ++m) {
        #pragma unroll
        for (int n = 0; n < 2; ++n) {
            #pragma unroll
            for (int r = 0; r < 4; ++r) {
                int grow = bm + wr * 32 + m * 16 + l4 * 4 + r;
                int gcol = bn + wc * 32 + n * 16 + l15;
                float val = acc[m][n][r];
                if (EPI == 0) {
                    if (gcol < Nn) C[(size_t)grow * ldc + gcol] = val * cscale;
                } else {
                    val += bias[gcol];
                    int reg = gcol >> 7, lc = gcol & 127;
                    if (reg == 0)      qb[grow * D + lc] = f2bf(val * SQRT_D_INV);
                    else if (reg == 1) kb[grow * D + lc] = f2bf(val);
                    else               vT[lc * N_PTS + grow] = f2bf(val);
                }
            }
        }
    }
}

// ------------------------------------------------------------------
// Fused attention scores: per 32x64 tile, MFMA S = q.k (pre-scaled),
// gather bias from P via vd indices, e = exp(s+b) (no max needed:
// |s|<~0.5), store bf16 unnormalized weights + per-(jblk,row) partial
// row sums (deterministic).
// ------------------------------------------------------------------
__global__ __launch_bounds__(256) void fused_attn_kernel(
    const u16* __restrict__ qb,   // 1024x128 bf16 (pre-scaled 1/sqrt(D))
    const u16* __restrict__ kb,   // 1024x128 bf16
    const float* __restrict__ P,  // 1024x1200 f32 (pre-scaled)
    const float* __restrict__ vd, // 1024x1024x3 f32
    u16* __restrict__ Sb,         // out: 1024x1024 bf16 exp-weights
    float* __restrict__ rowsumP)  // out: [16][1024] f32 partial sums
{
    __shared__ __align__(16) u16 As[32 * 128];
    __shared__ __align__(16) u16 Bs[64 * 128];
    __shared__ float rsw[2][32];
    const int tid = threadIdx.x;
    const int wave = tid >> 6, lane = tid & 63;
    const int wr = wave >> 1, wc = wave & 1;
    const int l15 = lane & 15, l4 = lane >> 4;
    const int bn = blockIdx.x * 64;   // j tile
    const int bm = blockIdx.y * 32;   // i tile

    #pragma unroll
    for (int r = 0; r < 2; ++r) {
        int unit = r * 256 + tid;
        int row = unit >> 4, c16 = unit & 15;
        int csw = c16 ^ (row & 7);
        const u16* ga = qb + (size_t)(bm + row) * D + csw * 8;
        __builtin_amdgcn_global_load_lds(
            (const GLOBAL_AS unsigned int*)ga,
            (LDS_AS unsigned int*)(As + r * 2048 + wave * 512), 16, 0, 0);
    }
    #pragma unroll
    for (int r = 0; r < 4; ++r) {
        int unit = r * 256 + tid;
        int row = unit >> 4, c16 = unit & 15;
        int csw = c16 ^ (row & 7);
        const u16* gb = kb + (size_t)(bn + row) * D + csw * 8;
        __builtin_amdgcn_global_load_lds(
            (const GLOBAL_AS unsigned int*)gb,
            (LDS_AS unsigned int*)(Bs + r * 2048 + wave * 512), 16, 0, 0);
    }
    __syncthreads();

    f32x4 acc[2] = {};
    #pragma unroll
    for (int ks = 0; ks < 4; ++ks) {
        int arow = wr * 16 + l15;
        int c16 = ks * 4 + l4;
        bf16x8 a = *(const bf16x8*)(As + arow * 128 + (c16 ^ (arow & 7)) * 8);
        #pragma unroll
        for (int n = 0; n < 2; ++n) {
            int brow = wc * 32 + n * 16 + l15;
            bf16x8 b = *(const bf16x8*)(Bs + brow * 128 + (c16 ^ (brow & 7)) * 8);
            acc[n] = __builtin_amdgcn_mfma_f32_16x16x32_bf16(a, b, acc[n], 0, 0, 0);
        }
    }

    float rsp[4];
    #pragma unroll
    for (int r = 0; r < 4; ++r) {
        int i = bm + wr * 16 + l4 * 4 + r;
        const float* Pi = P + (size_t)i * PLD;
        const float* vdi = vd + (size_t)i * N_PTS * 3;
        float rs = 0.0f;
        #pragma unroll
        for (int n = 0; n < 2; ++n) {
            int j = bn + wc * 32 + n * 16 + l15;
            const float* vp = vdi + j * 3;
            float x = vp[0], y = vp[1], z = vp[2];
            int ix = (int)floorf((x + 4.0f) / 0.02f);
            int iy = (int)floorf((y + 4.0f) / 0.02f);
            int iz = (int)floorf((z + 4.0f) / 0.02f);
            ix = min(max(ix, 0), QL - 1);
            iy = min(max(iy, 0), QL - 1);
            iz = min(max(iz, 0), QL - 1);
            float bv = Pi[ix] + Pi[QL + iy] + Pi[2 * QL + iz];
            float e = __expf(acc[n][r] + bv);
            rs += e;
            Sb[(size_t)i * N_PTS + j] = f2bf(e);
        }
        rsp[r] = rs;
    }
    #pragma unroll
    for (int r = 0; r < 4; ++r) {
        #pragma unroll
        for (int off = 1; off < 16; off <<= 1)
            rsp[r] += __shfl_xor(rsp[r], off);
    }
    if (l15 == 0) {
        #pragma unroll
        for (int r = 0; r < 4; ++r)
            rsw[wc][wr * 16 + l4 * 4 + r] = rsp[r];
    }
    __syncthreads();
    if (tid < 32)
        rowsumP[blockIdx.x * N_PTS + bm + tid] = rsw[0][tid] + rsw[1][tid];
}

// ------------------------------------------------------------------
// Reduce split-K partials + normalize by rowsum (fixed order).
// ------------------------------------------------------------------
__global__ __launch_bounds__(256) void reduce_norm_kernel(
    const float* __restrict__ part,      // [8][1024][128]
    const float* __restrict__ rowsumP,   // [16][1024]
    float* __restrict__ out)             // [1024][128]
{
    int e = blockIdx.x * 256 + threadIdx.x;   // float4 id, 32768 total
    int row = e >> 5;
    float rs = 0.0f;
    #pragma unroll
    for (int jb = 0; jb < 16; ++jb) rs += rowsumP[jb * N_PTS + row];
    float inv = 1.0f / rs;
    const float4* p4 = (const float4*)part;
    float4 a = p4[e];
    #pragma unroll
    for (int z = 1; z < 8; ++z) {
        float4 v = p4[(size_t)z * 32768 + e];
        a.x += v.x; a.y += v.y; a.z += v.z; a.w += v.w;
    }
    a.x *= inv; a.y *= inv; a.z *= inv; a.w *= inv;
    ((float4*)out)[e] = a;
}

// ------------------------------------------------------------------
extern "C" void kernel_launch(void* const* d_in, const int* in_sizes, int n_in,
                              void* d_out, int out_size, void* d_ws, size_t ws_size,
                              hipStream_t stream)
{
    const float* features = (const float*)d_in[0];  // 1024 x 128
    const float* vd       = (const float*)d_in[1];  // 1024 x 1024 x 3
    const float* W        = (const float*)d_in[2];  // 128 x 384
    const float* b        = (const float*)d_in[3];  // 384
    const float* tx       = (const float*)d_in[4];  // 3 x 400 x 128
    const float* ty       = (const float*)d_in[5];
    const float* tz       = (const float*)d_in[6];
    float* out = (float*)d_out;                     // 1024 x 128 f32

    char* w0 = (char*)d_ws;
    u16* fbf      = (u16*)w0;                       // 256 KB
    u16* Wt       = (u16*)(w0 + 0x40000);           // 96 KB
    u16* Tcat     = (u16*)(w0 + 0x60000);           // 300 KB
    u16* qb       = (u16*)(w0 + 0xB0000);           // 256 KB
    u16* kb       = (u16*)(w0 + 0xF0000);           // 256 KB
    u16* vT       = (u16*)(w0 + 0x130000);          // 256 KB (128x1024)
    u16* Sb       = (u16*)(w0 + 0x170000);          // 2 MB
    float* P      = (float*)(w0 + 0x370000);        // 4.8 MB
    float* rowsumP= (float*)(w0 + 0x820000);        // 64 KB  [16][1024]
    float* part   = (float*)(w0 + 0x830000);        // 4 MB   [8][1024][128]

    dim3 blk(256);

    // 0. converts
    convert_kernel<<<dim3((CVT_F + CVT_W + CVT_T) / 256), blk, 0, stream>>>(
        features, W, tx, ty, tz, fbf, Wt, Tcat);

    // 1. qkv = features @ W + b -> qb (scaled), kb, vT
    mfma_nt<1><<<dim3(384 / 64, N_PTS / 64, 1), blk, 0, stream>>>(
        fbf, D, Wt, D, 384, nullptr, 0, D, b, qb, kb, vT, 0, 0, 0, 1.0f);

    // 2. P = (k @ Tcat^T) * 1/sqrt(D)
    mfma_nt<0><<<dim3((PLD + 63) / 64, N_PTS / 64, 1), blk, 0, stream>>>(
        kb, D, Tcat, D, PLD, P, PLD, D, nullptr, nullptr, nullptr, nullptr,
        0, 0, 0, SQRT_D_INV);

    // 3. fused S + bias + exp -> Sb bf16, rowsumP
    fused_attn_kernel<<<dim3(16, 32, 1), blk, 0, stream>>>(
        qb, kb, P, vd, Sb, rowsumP);

    // 4. out partials = Sb @ vT, split-K=8 (256 blocks, one K-stage each)
    mfma_nt<0><<<dim3(2, 16, 8), blk, 0, stream>>>(
        Sb, N_PTS, vT, N_PTS, 128, part, D, 128, nullptr, nullptr, nullptr, nullptr,
        128, 128, (long)N_PTS * D, 1.0f);

    // 5. reduce + normalize
    reduce_norm_kernel<<<dim3(128, 1, 1), blk, 0, stream>>>(part, rowsumP, out);
}

// Round 4
// 29.060 us; speedup vs baseline: 4.3811x; 1.2784x over previous
//
#include <hip/hip_runtime.h>
#include <math.h>

#define N_PTS 1024
#define D 128
#define QL 400
#define PLD 1200            // 3*QL
#define SQRT_D_INV 0.08838834764831845f

typedef __attribute__((ext_vector_type(8))) short bf16x8;
typedef __attribute__((ext_vector_type(4))) float f32x4;
typedef unsigned short u16;

#define GLOBAL_AS __attribute__((address_space(1)))
#define LDS_AS    __attribute__((address_space(3)))

__device__ __forceinline__ u16 f2bf(float x) {
    union { float f; unsigned u; } v; v.f = x;
    unsigned r = v.u + 0x7fff + ((v.u >> 16) & 1);   // RNE
    return (u16)(r >> 16);
}
__device__ __forceinline__ float b2f(u16 h) {
    union { unsigned u; float f; } v; v.u = ((unsigned)h) << 16;
    return v.f;
}

// ------------------------------------------------------------------
// prep_kernel: blocks [0,96): qkv = features @ W + bias (f32 inputs,
// in-kernel bf16 convert), epilogue splits q (scaled 1/sqrt(D)), k, vT.
// blocks [96,246): convert tables[1] x|y|z -> Tcat (1200x128 bf16).
// ------------------------------------------------------------------
__global__ __launch_bounds__(256) void prep_kernel(
    const float* __restrict__ features, const float* __restrict__ W,
    const float* __restrict__ bias,
    const float* __restrict__ tx, const float* __restrict__ ty,
    const float* __restrict__ tz,
    u16* __restrict__ qb, u16* __restrict__ kb, u16* __restrict__ vT,
    u16* __restrict__ Tcat)
{
    __shared__ __align__(16) u16 As[64 * 128];
    __shared__ __align__(16) u16 Bs[64 * 128];
    const int tid = threadIdx.x;
    const int bx = blockIdx.x;

    if (bx >= 96) {
        // Tcat conversion: 150 blocks x 1024 elements
        int e0 = (bx - 96) * 1024 + tid * 4;
        int n = e0 >> 7, k = e0 & 127;
        int sec = n / QL, r = n - sec * QL;
        const float* t = (sec == 0) ? tx : ((sec == 1) ? ty : tz);
        float4 v = *(const float4*)&t[QL * D + r * D + k];
        ushort4 o;
        o.x = f2bf(v.x); o.y = f2bf(v.y); o.z = f2bf(v.z); o.w = f2bf(v.w);
        *(ushort4*)&Tcat[e0] = o;
        return;
    }

    const int wave = tid >> 6, lane = tid & 63;
    const int wr = wave >> 1, wc = wave & 1;
    const int l15 = lane & 15, l4 = lane >> 4;
    const int bm = (bx / 6) * 64;
    const int bn = (bx % 6) * 64;

    // A staging: features f32 -> bf16 LDS (swizzled), 4 rounds
    #pragma unroll
    for (int r0 = 0; r0 < 4; ++r0) {
        int unit = r0 * 256 + tid;
        int row = unit >> 4, c16 = unit & 15;
        const float* ga = features + (size_t)(bm + row) * D + c16 * 8;
        float4 a0 = *(const float4*)ga;
        float4 a1 = *(const float4*)(ga + 4);
        u16 h[8] = {f2bf(a0.x), f2bf(a0.y), f2bf(a0.z), f2bf(a0.w),
                    f2bf(a1.x), f2bf(a1.y), f2bf(a1.z), f2bf(a1.w)};
        *(bf16x8*)(As + row * 128 + ((c16 ^ (row & 7)) * 8)) = *(bf16x8*)h;
    }
    // B staging: W (128x384) transposed into Bs[n][k] bf16, 8 rounds
    #pragma unroll
    for (int r2 = 0; r2 < 8; ++r2) {
        int k = r2 * 16 + (tid >> 4);
        int nl = (tid & 15) * 4;
        float4 w4 = *(const float4*)&W[(size_t)k * 384 + bn + nl];
        float wv[4] = {w4.x, w4.y, w4.z, w4.w};
        #pragma unroll
        for (int e = 0; e < 4; ++e) {
            int n = nl + e;
            Bs[n * 128 + ((k >> 3) ^ (n & 7)) * 8 + (k & 7)] = f2bf(wv[e]);
        }
    }
    __syncthreads();

    f32x4 acc[2][2] = {};
    #pragma unroll
    for (int ks = 0; ks < 4; ++ks) {
        bf16x8 a[2], b[2];
        #pragma unroll
        for (int m = 0; m < 2; ++m) {
            int row = wr * 32 + m * 16 + l15;
            int c16 = ks * 4 + l4;
            a[m] = *(const bf16x8*)(As + row * 128 + ((c16 ^ (row & 7)) * 8));
        }
        #pragma unroll
        for (int n = 0; n < 2; ++n) {
            int row = wc * 32 + n * 16 + l15;
            int c16 = ks * 4 + l4;
            b[n] = *(const bf16x8*)(Bs + row * 128 + ((c16 ^ (row & 7)) * 8));
        }
        #pragma unroll
        for (int m = 0; m < 2; ++m)
            #pragma unroll
            for (int n = 0; n < 2; ++n)
                acc[m][n] = __builtin_amdgcn_mfma_f32_16x16x32_bf16(
                    a[m], b[n], acc[m][n], 0, 0, 0);
    }

    #pragma unroll
    for (int m = 0; m < 2; ++m) {
        #pragma unroll
        for (int n = 0; n < 2; ++n) {
            #pragma unroll
            for (int r = 0; r < 4; ++r) {
                int grow = bm + wr * 32 + m * 16 + l4 * 4 + r;
                int gcol = bn + wc * 32 + n * 16 + l15;
                float val = acc[m][n][r] + bias[gcol];
                int reg = gcol >> 7, lc = gcol & 127;
                if (reg == 0)      qb[grow * D + lc] = f2bf(val * SQRT_D_INV);
                else if (reg == 1) kb[grow * D + lc] = f2bf(val);
                else               vT[(size_t)lc * N_PTS + grow] = f2bf(val);
            }
        }
    }
}

// ------------------------------------------------------------------
// P GEMM: Pb[m,c] = (sum_k kb[m,k]*Tcat[c,k]) * 1/sqrt(D), bf16 out.
// 64x64 tile, single K-stage (K=128), global_load_lds staging.
// ------------------------------------------------------------------
__global__ __launch_bounds__(256) void p_gemm_kernel(
    const u16* __restrict__ A,      // kb 1024x128
    const u16* __restrict__ B,      // Tcat 1200x128
    u16* __restrict__ Cb)           // Pb 1024x1200 bf16
{
    __shared__ __align__(16) u16 As[64 * 128];
    __shared__ __align__(16) u16 Bs[64 * 128];
    const int tid  = threadIdx.x;
    const int wave = tid >> 6, lane = tid & 63;
    const int wr = wave >> 1, wc = wave & 1;
    const int l15 = lane & 15, l4 = lane >> 4;
    const int bm = blockIdx.y * 64, bn = blockIdx.x * 64;

    #pragma unroll
    for (int r = 0; r < 4; ++r) {
        int unit = r * 256 + tid;
        int row  = unit >> 4;
        int c16  = unit & 15;
        int csw  = c16 ^ (row & 7);
        const u16* ga = A + (size_t)(bm + row) * D + csw * 8;
        __builtin_amdgcn_global_load_lds(
            (const GLOBAL_AS unsigned int*)ga,
            (LDS_AS unsigned int*)(As + r * 2048 + wave * 512), 16, 0, 0);
        int brow = bn + row; if (brow > PLD - 1) brow = PLD - 1;
        const u16* gb = B + (size_t)brow * D + csw * 8;
        __builtin_amdgcn_global_load_lds(
            (const GLOBAL_AS unsigned int*)gb,
            (LDS_AS unsigned int*)(Bs + r * 2048 + wave * 512), 16, 0, 0);
    }
    __syncthreads();

    f32x4 acc[2][2] = {};
    #pragma unroll
    for (int ks = 0; ks < 4; ++ks) {
        bf16x8 a[2], b[2];
        #pragma unroll
        for (int m = 0; m < 2; ++m) {
            int row = wr * 32 + m * 16 + l15;
            int c16 = ks * 4 + l4;
            a[m] = *(const bf16x8*)(As + row * 128 + ((c16 ^ (row & 7)) * 8));
        }
        #pragma unroll
        for (int n = 0; n < 2; ++n) {
            int row = wc * 32 + n * 16 + l15;
            int c16 = ks * 4 + l4;
            b[n] = *(const bf16x8*)(Bs + row * 128 + ((c16 ^ (row & 7)) * 8));
        }
        #pragma unroll
        for (int m = 0; m < 2; ++m)
            #pragma unroll
            for (int n = 0; n < 2; ++n)
                acc[m][n] = __builtin_amdgcn_mfma_f32_16x16x32_bf16(
                    a[m], b[n], acc[m][n], 0, 0, 0);
    }

    #pragma unroll
    for (int m = 0; m < 2; ++m)
        #pragma unroll
        for (int n = 0; n < 2; ++n)
            #pragma unroll
            for (int r = 0; r < 4; ++r) {
                int grow = bm + wr * 32 + m * 16 + l4 * 4 + r;
                int gcol = bn + wc * 32 + n * 16 + l15;
                if (gcol < PLD)
                    Cb[(size_t)grow * PLD + gcol] = f2bf(acc[m][n][r] * SQRT_D_INV);
            }
}

// ------------------------------------------------------------------
// flash_kernel: block = (i-tile 16 rows, j-chunk 128 cols).
// Stage 16 P-rows (bf16) in LDS; Q/K/V fragments direct from global;
// QK^T MFMA -> bias gather (LDS) -> exp -> E tile to swizzled LDS ->
// PV MFMA -> f32 partials + partial rowsums.
// ------------------------------------------------------------------
__global__ __launch_bounds__(256) void flash_kernel(
    const u16* __restrict__ qb,   // 1024x128 (pre-scaled)
    const u16* __restrict__ kb,   // 1024x128
    const u16* __restrict__ vT,   // 128x1024
    const u16* __restrict__ Pb,   // 1024x1200 bf16 (pre-scaled)
    const float* __restrict__ vd, // 1024x1024x3
    float* __restrict__ part,     // [8][1024][128]
    float* __restrict__ rowsumP)  // [8][1024]
{
    __shared__ __align__(16) u16 Pl[2432 * 8];   // 16x1200 + 32-unit pad
    __shared__ __align__(16) u16 Ps[16 * 128];
    __shared__ float rsw[4][16];
    const int tid = threadIdx.x;
    const int wave = tid >> 6, lane = tid & 63;
    const int l15 = lane & 15, l4 = lane >> 4;
    const int bm = blockIdx.y * 16;
    const int bn = blockIdx.x * 128;

    // ---- stage P slab: 2400 16B-units flat copy ----
    const u16* Pg = Pb + (size_t)bm * PLD;
    #pragma unroll
    for (int r0 = 0; r0 < 9; ++r0) {
        int unit = r0 * 256 + tid;
        __builtin_amdgcn_global_load_lds(
            (const GLOBAL_AS unsigned int*)(Pg + unit * 8),
            (LDS_AS unsigned int*)(Pl + r0 * 2048 + wave * 512), 16, 0, 0);
    }
    if (wave < 2) {
        int unit = 9 * 256 + tid;
        int cu = unit > 2399 ? 2399 : unit;
        __builtin_amdgcn_global_load_lds(
            (const GLOBAL_AS unsigned int*)(Pg + cu * 8),
            (LDS_AS unsigned int*)(Pl + 9 * 2048 + wave * 512), 16, 0, 0);
    }

    // ---- early vd loads (T14): 8 slots (nn, r) ----
    float vx[2][4], vy[2][4], vz[2][4];
    #pragma unroll
    for (int nn = 0; nn < 2; ++nn)
        #pragma unroll
        for (int r = 0; r < 4; ++r) {
            int i = l4 * 4 + r;
            int j = wave * 32 + nn * 16 + l15;
            const float* vp = vd + ((size_t)(bm + i) * N_PTS + bn + j) * 3;
            vx[nn][r] = vp[0]; vy[nn][r] = vp[1]; vz[nn][r] = vp[2];
        }

    // ---- QK^T: per-wave 32-j quarter ----
    bf16x8 aq[4];
    #pragma unroll
    for (int ks = 0; ks < 4; ++ks)
        aq[ks] = *(const bf16x8*)(qb + (size_t)(bm + l15) * D + ks * 32 + l4 * 8);
    f32x4 acc[2] = {};
    #pragma unroll
    for (int nn = 0; nn < 2; ++nn) {
        int jt = bn + wave * 32 + nn * 16;
        #pragma unroll
        for (int ks = 0; ks < 4; ++ks) {
            bf16x8 bk = *(const bf16x8*)(kb + (size_t)(jt + l15) * D + ks * 32 + l4 * 8);
            acc[nn] = __builtin_amdgcn_mfma_f32_16x16x32_bf16(aq[ks], bk, acc[nn], 0, 0, 0);
        }
    }
    __syncthreads();   // Pl staged

    // ---- bias gather + exp + Ps write + rowsum ----
    float rs[4] = {0.f, 0.f, 0.f, 0.f};
    #pragma unroll
    for (int nn = 0; nn < 2; ++nn)
        #pragma unroll
        for (int r = 0; r < 4; ++r) {
            int i = l4 * 4 + r;
            int jl = wave * 32 + nn * 16 + l15;
            int ix = (int)floorf((vx[nn][r] + 4.0f) * 50.0f);
            int iy = (int)floorf((vy[nn][r] + 4.0f) * 50.0f);
            int iz = (int)floorf((vz[nn][r] + 4.0f) * 50.0f);
            ix = min(max(ix, 0), QL - 1);
            iy = min(max(iy, 0), QL - 1);
            iz = min(max(iz, 0), QL - 1);
            const u16* Pr = Pl + i * PLD;
            float bv = b2f(Pr[ix]) + b2f(Pr[QL + iy]) + b2f(Pr[2 * QL + iz]);
            float e = __expf(acc[nn][r] + bv);
            rs[r] += e;
            Ps[i * 128 + (((jl >> 3) ^ (i & 7)) * 8) + (jl & 7)] = f2bf(e);
        }
    #pragma unroll
    for (int r = 0; r < 4; ++r)
        #pragma unroll
        for (int off = 1; off < 16; off <<= 1)
            rs[r] += __shfl_xor(rs[r], off);
    if (l15 == 0)
        #pragma unroll
        for (int r = 0; r < 4; ++r) rsw[wave][l4 * 4 + r] = rs[r];
    __syncthreads();   // Ps + rsw ready
    if (tid < 16)
        rowsumP[blockIdx.x * N_PTS + bm + tid] =
            rsw[0][tid] + rsw[1][tid] + rsw[2][tid] + rsw[3][tid];

    // ---- PV: per-wave 32-d quarter ----
    bf16x8 pa[4];
    #pragma unroll
    for (int kt = 0; kt < 4; ++kt)
        pa[kt] = *(const bf16x8*)(Ps + l15 * 128 + (((kt * 4 + l4) ^ (l15 & 7)) * 8));
    f32x4 acc2[2] = {};
    #pragma unroll
    for (int nn = 0; nn < 2; ++nn) {
        int dt = wave * 32 + nn * 16;
        #pragma unroll
        for (int kt = 0; kt < 4; ++kt) {
            bf16x8 bv8 = *(const bf16x8*)(vT + (size_t)(dt + l15) * N_PTS + bn + kt * 32 + l4 * 8);
            acc2[nn] = __builtin_amdgcn_mfma_f32_16x16x32_bf16(pa[kt], bv8, acc2[nn], 0, 0, 0);
        }
    }
    float* po = part + (size_t)blockIdx.x * (N_PTS * D);
    #pragma unroll
    for (int nn = 0; nn < 2; ++nn)
        #pragma unroll
        for (int r = 0; r < 4; ++r)
            po[(size_t)(bm + l4 * 4 + r) * D + wave * 32 + nn * 16 + l15] = acc2[nn][r];
}

// ------------------------------------------------------------------
// reduce partials + normalize (fixed order, deterministic)
// ------------------------------------------------------------------
__global__ __launch_bounds__(256) void reduce_norm_kernel(
    const float* __restrict__ part,      // [8][1024][128]
    const float* __restrict__ rowsumP,   // [8][1024]
    float* __restrict__ out)             // [1024][128]
{
    int e = blockIdx.x * 256 + threadIdx.x;   // float4 id, 32768 total
    int row = e >> 5;
    float rs = 0.0f;
    #pragma unroll
    for (int jb = 0; jb < 8; ++jb) rs += rowsumP[jb * N_PTS + row];
    float inv = 1.0f / rs;
    const float4* p4 = (const float4*)part;
    float4 a = p4[e];
    #pragma unroll
    for (int z = 1; z < 8; ++z) {
        float4 v = p4[(size_t)z * 32768 + e];
        a.x += v.x; a.y += v.y; a.z += v.z; a.w += v.w;
    }
    a.x *= inv; a.y *= inv; a.z *= inv; a.w *= inv;
    ((float4*)out)[e] = a;
}

// ------------------------------------------------------------------
extern "C" void kernel_launch(void* const* d_in, const int* in_sizes, int n_in,
                              void* d_out, int out_size, void* d_ws, size_t ws_size,
                              hipStream_t stream)
{
    const float* features = (const float*)d_in[0];  // 1024 x 128
    const float* vd       = (const float*)d_in[1];  // 1024 x 1024 x 3
    const float* W        = (const float*)d_in[2];  // 128 x 384
    const float* b        = (const float*)d_in[3];  // 384
    const float* tx       = (const float*)d_in[4];  // 3 x 400 x 128
    const float* ty       = (const float*)d_in[5];
    const float* tz       = (const float*)d_in[6];
    float* out = (float*)d_out;                     // 1024 x 128 f32

    char* w0 = (char*)d_ws;
    u16* qb       = (u16*)w0;                       // 256 KB
    u16* kb       = (u16*)(w0 + 0x40000);           // 256 KB
    u16* vT       = (u16*)(w0 + 0x80000);           // 256 KB (128x1024)
    u16* Tcat     = (u16*)(w0 + 0xC0000);           // 300 KB
    u16* Pb       = (u16*)(w0 + 0x110000);          // 2.4 MB (1024x1200 bf16)
    float* part   = (float*)(w0 + 0x370000);        // 4 MB   [8][1024][128]
    float* rowsumP= (float*)(w0 + 0x770000);        // 32 KB  [8][1024]

    dim3 blk(256);

    // 1. qkv (+bias, q pre-scaled) + Tcat convert, one dispatch
    prep_kernel<<<dim3(246), blk, 0, stream>>>(
        features, W, b, tx, ty, tz, qb, kb, vT, Tcat);

    // 2. Pb = (kb @ Tcat^T) * 1/sqrt(D), bf16
    p_gemm_kernel<<<dim3(19, 16), blk, 0, stream>>>(kb, Tcat, Pb);

    // 3. flash: S+bias+exp+PV partials
    flash_kernel<<<dim3(8, 64), blk, 0, stream>>>(
        qb, kb, vT, Pb, vd, part, rowsumP);

    // 4. reduce + normalize
    reduce_norm_kernel<<<dim3(128), blk, 0, stream>>>(part, rowsumP, out);
}